// Round 11
// baseline (467.781 us; speedup 1.0000x reference)
//
#include <hip/hip_runtime.h>
#include <stdint.h>

// ============================================================================
// JAX threefry2x32 PRNG reproduction (partitionable semantics, verified R0).
// ============================================================================
struct U2 { unsigned a, b; };

__device__ __forceinline__ unsigned rotl32(unsigned v, int r) {
  return (v << r) | (v >> (32 - r));
}

__device__ __forceinline__ U2 tf(U2 k, unsigned x0, unsigned x1) {
  unsigned ks0 = k.a, ks1 = k.b, ks2 = k.a ^ k.b ^ 0x1BD11BDAu;
  x0 += ks0; x1 += ks1;
#define TFG(RA, RB, RC, RD, KA, KB, INC)                  \
  x0 += x1; x1 = rotl32(x1, RA); x1 ^= x0;                \
  x0 += x1; x1 = rotl32(x1, RB); x1 ^= x0;                \
  x0 += x1; x1 = rotl32(x1, RC); x1 ^= x0;                \
  x0 += x1; x1 = rotl32(x1, RD); x1 ^= x0;                \
  x0 += KA; x1 += KB + INC;
  TFG(13, 15, 26, 6, ks1, ks2, 1u)
  TFG(17, 29, 16, 24, ks2, ks0, 2u)
  TFG(13, 15, 26, 6, ks0, ks1, 3u)
  TFG(17, 29, 16, 24, ks1, ks2, 4u)
  TFG(13, 15, 26, 6, ks2, ks0, 5u)
#undef TFG
  U2 r; r.a = x0; r.b = x1; return r;
}

__device__ __forceinline__ U2 split_key(U2 key, int num, int j) {
  (void)num;
  return tf(key, 0u, (unsigned)j);
}
__device__ __forceinline__ unsigned random_bits(U2 key, int n, unsigned e) {
  (void)n;
  U2 r = tf(key, 0u, e);
  return r.a ^ r.b;
}

__device__ __forceinline__ U2 root_key() { U2 k; k.a = 0u; k.b = 42u; return k; }

__device__ __forceinline__ float jax_uniform(U2 key, int n, unsigned e,
                                             float minv, float maxv) {
  unsigned b = random_bits(key, n, e);
  float u = __uint_as_float((b >> 9) | 0x3f800000u) - 1.0f;
  float r = u * (maxv - minv) + minv;
  return fmaxf(minv, r);
}

#define ROTR 0.7853981633974483f

__device__ __forceinline__ void compute_R(float vx, float vy, float vz,
                                          float R[3][3]) {
  float nsq = vx * vx + vy * vy + vz * vz;
  float theta = sqrtf(nsq);
  if (theta < 1e-8f) {
    R[0][0] = 1.f; R[0][1] = 0.f; R[0][2] = 0.f;
    R[1][0] = 0.f; R[1][1] = 1.f; R[1][2] = 0.f;
    R[2][0] = 0.f; R[2][1] = 0.f; R[2][2] = 1.f;
    return;
  }
  float m = fmaxf(theta, 1e-8f);
  float kx = vx / m, ky = vy / m, kz = vz / m;
  float s = sinf(theta), c = cosf(theta);
  float K[3][3] = {{0.f, -kz, ky}, {kz, 0.f, -kx}, {-ky, kx, 0.f}};
  float K2[3][3];
#pragma unroll
  for (int i = 0; i < 3; i++)
#pragma unroll
    for (int j = 0; j < 3; j++)
      K2[i][j] = fmaf(K[i][2], K[2][j], fmaf(K[i][1], K[1][j], K[i][0] * K[0][j]));
  float omc = 1.0f - c;
#pragma unroll
  for (int i = 0; i < 3; i++)
#pragma unroll
    for (int j = 0; j < 3; j++)
      R[i][j] = ((i == j) ? 1.0f : 0.0f) + s * K[i][j] + omc * K2[i][j];
}

// composite sort key for stream s (0:src r1, 1:src r2, 2:tgt r1, 3:tgt r2)
__device__ __forceinline__ unsigned long long make_composite(int s, int i) {
  U2 root = root_key();
  U2 kp = split_key(root, 5, s >> 1);
  U2 key;
  if ((s & 1) == 0) {
    key = split_key(kp, 2, 1);
  } else {
    U2 kA = split_key(kp, 2, 0);
    key = split_key(kA, 2, 1);
  }
  unsigned rb = random_bits(key, 16384, (unsigned)i);
  return ((unsigned long long)rb << 32) | (unsigned)i;
}

// ============================================================================
// Bucket-sort rank pipeline (verified R3-R6/R10) — WIDE dispatches.
// ============================================================================
__global__ __launch_bounds__(256) void hist_kernel(unsigned* __restrict__ hist) {
  int gid = blockIdx.x * 256 + threadIdx.x;  // 65536
  int s = gid >> 14, i = gid & 16383;
  unsigned long long c = make_composite(s, i);
  unsigned bucket = (unsigned)(c >> 56);
  atomicAdd(&hist[s * 256 + bucket], 1u);
}

__global__ __launch_bounds__(256) void prefix_kernel(
    const unsigned* __restrict__ hist, unsigned* __restrict__ base,
    unsigned* __restrict__ cursor) {
  __shared__ unsigned h[4][256];
  int t = threadIdx.x;
#pragma unroll
  for (int s = 0; s < 4; s++) h[s][t] = hist[s * 256 + t];
  __syncthreads();
#pragma unroll
  for (int s = 0; s < 4; s++) {
    unsigned acc = 0;
    for (int j = 0; j < 256; j++) acc += (j < t) ? h[s][j] : 0u;
    base[s * 256 + t] = acc;
    cursor[s * 256 + t] = acc;
  }
}

__global__ __launch_bounds__(256) void scatterb_kernel(
    unsigned* __restrict__ cursor, unsigned long long* __restrict__ sorted) {
  int gid = blockIdx.x * 256 + threadIdx.x;  // 65536
  int s = gid >> 14, i = gid & 16383;
  unsigned long long c = make_composite(s, i);
  unsigned bucket = (unsigned)(c >> 56);
  unsigned pos = atomicAdd(&cursor[s * 256 + bucket], 1u);
  sorted[(s << 14) + pos] = c;
}

__global__ __launch_bounds__(256) void rank_kernel(
    const unsigned long long* __restrict__ sorted,
    const unsigned* __restrict__ base, const unsigned* __restrict__ hist,
    unsigned* __restrict__ rank_all) {
  int gid = blockIdx.x * 256 + threadIdx.x;  // 65536
  int s = gid >> 14, k = gid & 16383;
  unsigned long long c = sorted[(s << 14) + k];
  unsigned bucket = (unsigned)(c >> 56);
  unsigned b0 = base[s * 256 + bucket];
  unsigned cnt = hist[s * 256 + bucket];
  unsigned less = 0;
  for (unsigned j = 0; j < cnt; j++)
    less += (sorted[(s << 14) + b0 + j] < c) ? 1u : 0u;
  unsigned i = (unsigned)(c & 0xffffffffull);
  rank_all[(s << 14) + i] = b0 + less;
}

__global__ __launch_bounds__(256) void scatter_kernel(
    const unsigned* __restrict__ rank_all, unsigned* __restrict__ x1buf) {
  int gid = blockIdx.x * 256 + threadIdx.x;  // 32768
  int perm = gid >> 14, i = gid & 16383;
  unsigned r = rank_all[((perm * 2) << 14) + i];
  x1buf[(perm << 14) + (int)r] = (unsigned)i;
}

__global__ __launch_bounds__(256) void idx_kernel(
    const unsigned* __restrict__ rank_all, const unsigned* __restrict__ x1buf,
    int* __restrict__ idx) {
  int gid = blockIdx.x * 256 + threadIdx.x;  // 32768
  int perm = gid >> 14, i = gid & 16383;
  unsigned r = rank_all[((perm * 2 + 1) << 14) + i];
  if (r < 128u) idx[perm * 128 + (int)r] = (int)x1buf[(perm << 14) + i];
}

// ============================================================================
// Chamfer eval core (verified R6 — bitwise identical d2/min/sum path).
// lt in [0,128); LDS pointers are group-local. All 3 __syncthreads are
// block-wide and hit uniformly by both groups.
// ============================================================================
__device__ __forceinline__ float eval_pose_core(
    float p0, float p1, float p2, float p3, float p4, float p5,
    float s0, float s1, float s2, int lt, const float4* syv, float4* xsv,
    float* rowpart, float* red1, float* red2) {
  float Rm[3][3];
  compute_R(p0, p1, p2, Rm);
  float x0 = fmaf(Rm[0][2], s2, fmaf(Rm[0][1], s1, Rm[0][0] * s0)) + p3;
  float x1 = fmaf(Rm[1][2], s2, fmaf(Rm[1][1], s1, Rm[1][0] * s0)) + p4;
  float x2 = fmaf(Rm[2][2], s2, fmaf(Rm[2][1], s1, Rm[2][0] * s0)) + p5;
  float xn = x0 * x0 + x1 * x1 + x2 * x2;
  xsv[lt] = make_float4(x0, x1, x2, xn);
  __syncthreads();
  int rg = lt & 31, cq = lt >> 5;
  float4 xr0 = xsv[4 * rg + 0];
  float4 xr1 = xsv[4 * rg + 1];
  float4 xr2 = xsv[4 * rg + 2];
  float4 xr3 = xsv[4 * rg + 3];
  float racc0 = 3.402823466e38f, racc1 = 3.402823466e38f;
  float racc2 = 3.402823466e38f, racc3 = 3.402823466e38f;
  float cacc[32];
#pragma unroll
  for (int cj = 0; cj < 32; cj++) {
    float4 y = syv[(cq << 5) + cj];
    float cr0 = fmaf(xr0.z, y.z, fmaf(xr0.y, y.y, xr0.x * y.x));
    float d0 = (xr0.w + y.w) - 2.0f * cr0; d0 = fmaxf(d0, 0.0f);
    float cr1 = fmaf(xr1.z, y.z, fmaf(xr1.y, y.y, xr1.x * y.x));
    float d1 = (xr1.w + y.w) - 2.0f * cr1; d1 = fmaxf(d1, 0.0f);
    float cr2 = fmaf(xr2.z, y.z, fmaf(xr2.y, y.y, xr2.x * y.x));
    float d2_ = (xr2.w + y.w) - 2.0f * cr2; d2_ = fmaxf(d2_, 0.0f);
    float cr3 = fmaf(xr3.z, y.z, fmaf(xr3.y, y.y, xr3.x * y.x));
    float d3 = (xr3.w + y.w) - 2.0f * cr3; d3 = fmaxf(d3, 0.0f);
    racc0 = fminf(racc0, d0); racc1 = fminf(racc1, d1);
    racc2 = fminf(racc2, d2_); racc3 = fminf(racc3, d3);
    cacc[cj] = fminf(fminf(d0, d1), fminf(d2_, d3));
  }
  rowpart[cq * 128 + 4 * rg + 0] = racc0;
  rowpart[cq * 128 + 4 * rg + 1] = racc1;
  rowpart[cq * 128 + 4 * rg + 2] = racc2;
  rowpart[cq * 128 + 4 * rg + 3] = racc3;
#pragma unroll
  for (int m = 16; m >= 1; m >>= 1) {
    bool hi = (rg & m) != 0;
#pragma unroll
    for (int j = 0; j < m; j++) {
      float lo_v = cacc[j], hi_v = cacc[j + m];
      float mine = hi ? hi_v : lo_v;
      float send = hi ? lo_v : hi_v;
      float recv = __shfl_xor(send, m, 64);
      cacc[j] = fminf(mine, recv);
    }
  }
  float colmin = cacc[0];
  __syncthreads();
  float rv = rowpart[lt];
  rv = fminf(rv, rowpart[128 + lt]);
  rv = fminf(rv, rowpart[256 + lt]);
  rv = fminf(rv, rowpart[384 + lt]);
  red1[lt] = rv;
  red2[lt] = colmin;
  __syncthreads();
  int l = lt & 63;
  float v1 = red1[l] + red1[l + 64];
  float v2 = red2[l] + red2[l + 64];
#pragma unroll
  for (int m = 32; m >= 1; m >>= 1) {
    v1 += __shfl_xor(v1, m, 64);
    v2 += __shfl_xor(v2, m, 64);
  }
  return v1 * 0.0078125f + v2 * 0.0078125f;
}

__device__ __forceinline__ float eff_pop(const float* pop_prev,
                                         const float* fit_prev,
                                         const float* trial_prev,
                                         const float* tfit_prev,
                                         int bq, int d) {
  return (tfit_prev[bq] < fit_prev[bq]) ? trial_prev[bq * 6 + d]
                                        : pop_prev[bq * 6 + d];
}

// pop0 value for particle r, dim d of batch b (pure function)
__device__ __forceinline__ float pop0_val(int b, int r, int d) {
  if (r == 0) return 0.0f;
  U2 root = root_key();
  unsigned ridx = (unsigned)((b * 50 + r) * 3 + (d % 3));
  if (d < 3) {
    U2 k2 = split_key(root, 5, 2);
    return jax_uniform(k2, 4800, ridx, -ROTR, ROTR);
  }
  U2 k3 = split_key(root, 5, 3);
  return jax_uniform(k3, 4800, ridx, -1.0f, 1.0f);
}

// ============================================================================
// fused DE step: 2 particles per block (256 threads = 2x128-thread groups
// sharing syv). init (it==0): worker blocks 0..799 gather src/tgt via idx,
// derive their own it=0 DE schedule in-block (R9 rank-count math), recompute
// pop0 rows, eval pop0 + trial0; blocks 800..1727 write packg for it=1..29;
// pu==0 worker block materializes srcb/tgtb/ynb for later steps.
// ============================================================================
__global__ __launch_bounds__(256, 4) void step_kernel(
    const float* __restrict__ source, const float* __restrict__ target,
    const int* __restrict__ idx,
    const float* __restrict__ srcb, const float* __restrict__ tgtb,
    const float* __restrict__ ynb, unsigned* __restrict__ packg,
    float* __restrict__ srcb_w, float* __restrict__ tgtb_w,
    float* __restrict__ ynb_w,
    const float* __restrict__ pop_prev, const float* __restrict__ fit_prev,
    const float* __restrict__ trial_prev, const float* __restrict__ tfit_prev,
    float* __restrict__ pop_cur, float* __restrict__ fit_cur,
    float* __restrict__ trial_cur, float* __restrict__ tfit_cur,
    int it, int init) {
  int blk = blockIdx.x;
  int tid = threadIdx.x;

  // ---- packg-writer blocks (init dispatch only) ----
  if (init && blk >= 800) {
    int blk2 = blk - 800;            // 0..927
    int itv = (blk2 >> 5) + 1;       // 1..29
    int b = blk2 & 31;
    __shared__ unsigned pbits[3][64];
    __shared__ int lperm[3][64];
    U2 root = root_key();
    U2 kloop = split_key(root, 5, 4);
    U2 kit = split_key(kloop, 30, itv);
    U2 ka = split_key(kit, 3, 0);
    for (int e = tid; e < 150; e += 256) {
      int r = e / 50, q = e % 50;
      U2 pk = split_key(ka, 96, r * 32 + b);
      U2 sub = split_key(pk, 2, 1);
      pbits[r][q] = random_bits(sub, 50, (unsigned)q);
    }
    __syncthreads();
    for (int e = tid; e < 150; e += 256) {
      int r = e / 50, q = e % 50;
      unsigned bq = pbits[r][q];
      int cnt = 0;
      for (int j = 0; j < 50; j++) {
        unsigned bj = pbits[r][j];
        cnt += (bj < bq || (bj == bq && j < q)) ? 1 : 0;
      }
      lperm[r][cnt] = q;
    }
    __syncthreads();
    if (tid < 50) {
      int p = tid, bp = b * 50 + p;
      U2 kb = split_key(kit, 3, 1);
      U2 kc = split_key(kit, 3, 2);
      U2 kc1 = split_key(kc, 2, 0), kc2 = split_key(kc, 2, 1);
      unsigned hb = random_bits(kc1, 1600, (unsigned)bp);
      unsigned lb = random_bits(kc2, 1600, (unsigned)bp);
      int jr = (int)((((hb % 6u) * 4u) + (lb % 6u)) % 6u);
      unsigned mask = 0;
#pragma unroll
      for (int d = 0; d < 6; d++) {
        unsigned rb = random_bits(kb, 9600, (unsigned)(bp * 6 + d));
        float u = __uint_as_float((rb >> 9) | 0x3f800000u) - 1.0f;
        if ((u < 0.9f) || (d == jr)) mask |= (1u << d);
      }
      packg[(itv * 32 + b) * 50 + p] = (unsigned)lperm[0][p] |
                                       ((unsigned)lperm[1][p] << 6) |
                                       ((unsigned)lperm[2][p] << 12) |
                                       (mask << 18);
    }
    return;
  }

  // ---- worker blocks: 800, 2 particles each ----
  int b = blk / 25, pu = blk % 25;
  int g = tid >> 7, lt = tid & 127;
  int p = 2 * pu + g;
  int bp = b * 50 + p;

  __shared__ float4 syv[128];
  __shared__ float4 xsv[2][128];
  __shared__ float rowpart[2][512];
  __shared__ float red1[2][128];
  __shared__ float red2[2][128];
  __shared__ float strial[2][8];

  float s0, s1, s2;

  if (init) {
    // gather via idx (both groups redundantly; values identical)
    int is = idx[lt];
    s0 = source[((size_t)b * 16384 + is) * 3 + 0];
    s1 = source[((size_t)b * 16384 + is) * 3 + 1];
    s2 = source[((size_t)b * 16384 + is) * 3 + 2];
    if (tid < 128) {
      int itg = idx[128 + lt];
      float y0 = target[((size_t)b * 16384 + itg) * 3 + 0];
      float y1 = target[((size_t)b * 16384 + itg) * 3 + 1];
      float y2 = target[((size_t)b * 16384 + itg) * 3 + 2];
      float yw = y0 * y0 + y1 * y1 + y2 * y2;
      syv[lt] = make_float4(y0, y1, y2, yw);
      if (pu == 0) {
        srcb_w[(b * 128 + lt) * 3 + 0] = s0;
        srcb_w[(b * 128 + lt) * 3 + 1] = s1;
        srcb_w[(b * 128 + lt) * 3 + 2] = s2;
        tgtb_w[(b * 128 + lt) * 3 + 0] = y0;
        tgtb_w[(b * 128 + lt) * 3 + 1] = y1;
        tgtb_w[(b * 128 + lt) * 3 + 2] = y2;
        ynb_w[b * 128 + lt] = yw;
      }
    }
    // in-block it=0 DE schedule (R9 rank-count math, batch-level shared)
    __shared__ unsigned pbits[3][64];
    __shared__ int lperm[3][64];
    __shared__ unsigned rbb[2][8];
    __shared__ unsigned smask[2];
    __shared__ int sidx[2][3];
    __shared__ float pv4[2][4][6];
    U2 root = root_key();
    U2 kloop = split_key(root, 5, 4);
    U2 kit = split_key(kloop, 30, 0);
    U2 ka = split_key(kit, 3, 0);
    for (int e = tid; e < 150; e += 256) {
      int r = e / 50, q = e % 50;
      U2 pk = split_key(ka, 96, r * 32 + b);
      U2 sub = split_key(pk, 2, 1);
      pbits[r][q] = random_bits(sub, 50, (unsigned)q);
    }
    __syncthreads();
    for (int e = tid; e < 150; e += 256) {
      int r = e / 50, q = e % 50;
      unsigned bq = pbits[r][q];
      int cnt = 0;
      for (int j = 0; j < 50; j++) {
        unsigned bj = pbits[r][j];
        cnt += (bj < bq || (bj == bq && j < q)) ? 1 : 0;
      }
      lperm[r][cnt] = q;
    }
    __syncthreads();
    {
      U2 kb = split_key(kit, 3, 1);
      U2 kc = split_key(kit, 3, 2);
      if (lt < 6) {
        rbb[g][lt] = random_bits(kb, 9600, (unsigned)(bp * 6 + lt));
      } else if (lt == 6) {
        U2 kc1 = split_key(kc, 2, 0);
        rbb[g][6] = random_bits(kc1, 1600, (unsigned)bp);
      } else if (lt == 7) {
        U2 kc2 = split_key(kc, 2, 1);
        rbb[g][7] = random_bits(kc2, 1600, (unsigned)bp);
      } else if (lt == 8) {
        sidx[g][0] = lperm[0][p];
        sidx[g][1] = lperm[1][p];
        sidx[g][2] = lperm[2][p];
      }
    }
    __syncthreads();
    if (lt == 0) {
      int jr = (int)((((rbb[g][6] % 6u) * 4u) + (rbb[g][7] % 6u)) % 6u);
      unsigned mask = 0;
#pragma unroll
      for (int d = 0; d < 6; d++) {
        float u = __uint_as_float((rbb[g][d] >> 9) | 0x3f800000u) - 1.0f;
        if ((u < 0.9f) || (d == jr)) mask |= (1u << d);
      }
      smask[g] = mask;
    }
    if (lt >= 32 && lt < 56) {
      int u = (lt - 32) / 6, d = (lt - 32) % 6;
      int rows[4] = {p, sidx[g][0], sidx[g][1], sidx[g][2]};
      pv4[g][u][d] = pop0_val(b, rows[u], d);
    }
    __syncthreads();
    float f0 = eval_pose_core(pv4[g][0][0], pv4[g][0][1], pv4[g][0][2],
                              pv4[g][0][3], pv4[g][0][4], pv4[g][0][5],
                              s0, s1, s2, lt, syv, xsv[g], rowpart[g],
                              red1[g], red2[g]);
    if (lt == 0) fit_cur[bp] = f0;
    if (lt < 6) {
      int d = lt;
      float mu = pv4[g][1][d] + 0.8f * (pv4[g][2][d] - pv4[g][3][d]);
      if (d < 3) mu = fminf(fmaxf(mu, -ROTR), ROTR);
      else       mu = fminf(fmaxf(mu, -1.0f), 1.0f);
      float pv = pv4[g][0][d];
      float tv = ((smask[g] >> d) & 1u) ? mu : pv;
      strial[g][d] = tv;
      trial_cur[bp * 6 + d] = tv;
      pop_cur[bp * 6 + d] = pv;
    }
    __syncthreads();
    float f = eval_pose_core(strial[g][0], strial[g][1], strial[g][2],
                             strial[g][3], strial[g][4], strial[g][5],
                             s0, s1, s2, lt, syv, xsv[g], rowpart[g],
                             red1[g], red2[g]);
    if (lt == 0) tfit_cur[bp] = f;
    return;
  }

  // ---- steady-state step ----
  if (tid < 128) {
    float y0 = tgtb[(b * 128 + lt) * 3 + 0];
    float y1 = tgtb[(b * 128 + lt) * 3 + 1];
    float y2 = tgtb[(b * 128 + lt) * 3 + 2];
    syv[lt] = make_float4(y0, y1, y2, ynb[b * 128 + lt]);
  }
  s0 = srcb[(b * 128 + lt) * 3 + 0];
  s1 = srcb[(b * 128 + lt) * 3 + 1];
  s2 = srcb[(b * 128 + lt) * 3 + 2];

  unsigned pack = packg[(it * 32 + b) * 50 + p];
  int i1 = (int)(pack & 63u);
  int i2 = (int)((pack >> 6) & 63u);
  int i3 = (int)((pack >> 12) & 63u);
  unsigned mask = (pack >> 18) & 63u;

  if (lt < 6) {
    int d = lt;
    float x1v = eff_pop(pop_prev, fit_prev, trial_prev, tfit_prev, b * 50 + i1, d);
    float x2v = eff_pop(pop_prev, fit_prev, trial_prev, tfit_prev, b * 50 + i2, d);
    float x3v = eff_pop(pop_prev, fit_prev, trial_prev, tfit_prev, b * 50 + i3, d);
    float mu = x1v + 0.8f * (x2v - x3v);
    if (d < 3) mu = fminf(fmaxf(mu, -ROTR), ROTR);
    else       mu = fminf(fmaxf(mu, -1.0f), 1.0f);
    float pv = eff_pop(pop_prev, fit_prev, trial_prev, tfit_prev, bp, d);
    float tv = ((mask >> d) & 1u) ? mu : pv;
    strial[g][d] = tv;
    trial_cur[bp * 6 + d] = tv;
    pop_cur[bp * 6 + d] = pv;
  } else if (lt == 6) {
    float f = fit_prev[bp], tfv = tfit_prev[bp];
    fit_cur[bp] = (tfv < f) ? tfv : f;
  }
  __syncthreads();

  float f = eval_pose_core(strial[g][0], strial[g][1], strial[g][2],
                           strial[g][3], strial[g][4], strial[g][5],
                           s0, s1, s2, lt, syv, xsv[g], rowpart[g],
                           red1[g], red2[g]);
  if (lt == 0) tfit_cur[bp] = f;
}

// ============================================================================
// aligned + final selection fused (verified R6/R10).
// ============================================================================
__global__ __launch_bounds__(256) void aligned_kernel(
    const float* __restrict__ source, const float* __restrict__ fit,
    const float* __restrict__ tfit, const float* __restrict__ pop,
    const float* __restrict__ trial, float* __restrict__ out) {
  int blk = blockIdx.x;  // 2048; 64 blocks per batch
  int b = blk >> 6;
  int tid = threadIdx.x;
  __shared__ float fl[64];
  __shared__ float Rsh[12];
  if (tid < 50) {
    int bp = b * 50 + tid;
    float f = fit[bp], tfv = tfit[bp];
    fl[tid] = (tfv < f) ? tfv : f;
  }
  __syncthreads();
  if (tid == 0) {
    int best = 0;
    for (int q = 1; q < 50; q++)
      if (fl[q] < fl[best]) best = q;
    int bp = b * 50 + best;
    bool useT = tfit[bp] < fit[bp];
    const float* v = useT ? (trial + bp * 6) : (pop + bp * 6);
    float R[3][3];
    compute_R(v[0], v[1], v[2], R);
#pragma unroll
    for (int i = 0; i < 3; i++)
#pragma unroll
      for (int j = 0; j < 3; j++) Rsh[i * 3 + j] = R[i][j];
    Rsh[9] = v[3]; Rsh[10] = v[4]; Rsh[11] = v[5];
    if ((blk & 63) == 0) {
#pragma unroll
      for (int e = 0; e < 9; e++) out[b * 9 + e] = Rsh[e];
      out[288 + b * 3 + 0] = v[3];
      out[288 + b * 3 + 1] = v[4];
      out[288 + b * 3 + 2] = v[5];
    }
  }
  __syncthreads();
  int gid = blk * 256 + tid;  // 524288
  float s0 = source[(size_t)gid * 3 + 0];
  float s1 = source[(size_t)gid * 3 + 1];
  float s2 = source[(size_t)gid * 3 + 2];
  float a0 = fmaf(Rsh[2], s2, fmaf(Rsh[1], s1, Rsh[0] * s0)) + Rsh[9];
  float a1 = fmaf(Rsh[5], s2, fmaf(Rsh[4], s1, Rsh[3] * s0)) + Rsh[10];
  float a2 = fmaf(Rsh[8], s2, fmaf(Rsh[7], s1, Rsh[6] * s0)) + Rsh[11];
  out[384 + (size_t)gid * 3 + 0] = a0;
  out[384 + (size_t)gid * 3 + 1] = a1;
  out[384 + (size_t)gid * 3 + 2] = a2;
}

// ============================================================================
extern "C" void kernel_launch(void* const* d_in, const int* in_sizes, int n_in,
                              void* d_out, int out_size, void* d_ws,
                              size_t ws_size, hipStream_t stream) {
  const float* source = (const float*)d_in[0];
  const float* target = (const float*)d_in[1];
  float* out = (float*)d_out;
  char* ws = (char*)d_ws;

  // --- workspace layout, fully disjoint ---
  unsigned long long* sorted = (unsigned long long*)(ws + 0);   // 524288
  unsigned* rank_all = (unsigned*)(ws + 524288);                // 262144
  unsigned* x1buf    = (unsigned*)(ws + 786432);                // 131072
  int* idx           = (int*)(ws + 917504);                     // 1024
  unsigned* hist     = (unsigned*)(ws + 918528);                // 4096
  unsigned* basep    = (unsigned*)(ws + 922624);                // 4096
  unsigned* cursor   = (unsigned*)(ws + 926720);                // 4096
  unsigned* packg    = (unsigned*)(ws + 930816);                // 192000
  float* srcb        = (float*)(ws + 1122816);                  // 49152
  float* tgtb        = (float*)(ws + 1171968);                  // 49152
  float* ynb         = (float*)(ws + 1221120);                  // 16384
  float* popA        = (float*)(ws + 1237504);                  // 38400
  float* fitA        = (float*)(ws + 1275904);                  // 6400
  float* trialA      = (float*)(ws + 1282304);                  // 38400
  float* tfitA       = (float*)(ws + 1320704);                  // 6400
  float* popB        = (float*)(ws + 1327104);                  // 38400
  float* fitB        = (float*)(ws + 1365504);                  // 6400
  float* trialB      = (float*)(ws + 1371904);                  // 38400
  float* tfitB       = (float*)(ws + 1410304);                  // 6400

  hipMemsetAsync(hist, 0, 4096, stream);
  hist_kernel<<<256, 256, 0, stream>>>(hist);
  prefix_kernel<<<1, 256, 0, stream>>>(hist, basep, cursor);
  scatterb_kernel<<<256, 256, 0, stream>>>(cursor, sorted);
  rank_kernel<<<256, 256, 0, stream>>>(sorted, basep, hist, rank_all);
  scatter_kernel<<<128, 256, 0, stream>>>(rank_all, x1buf);
  idx_kernel<<<128, 256, 0, stream>>>(rank_all, x1buf, idx);

  const float* pp = popA; const float* pf = fitA;
  const float* pt = trialA; const float* ptf = tfitA;
  for (int it = 0; it < 30; it++) {
    float* cp  = (it & 1) ? popB : popA;
    float* cf  = (it & 1) ? fitB : fitA;
    float* ct  = (it & 1) ? trialB : trialA;
    float* ctf = (it & 1) ? tfitB : tfitA;
    int init = (it == 0) ? 1 : 0;
    int grid = init ? 1728 : 800;  // 800 workers (+928 packg writers at it=0)
    step_kernel<<<grid, 256, 0, stream>>>(source, target, idx,
                                          srcb, tgtb, ynb, packg,
                                          srcb, tgtb, ynb,
                                          pp, pf, pt, ptf,
                                          cp, cf, ct, ctf, it, init);
    pp = cp; pf = cf; pt = ct; ptf = ctf;
  }
  // it=29 (odd) wrote the B buffers
  aligned_kernel<<<2048, 256, 0, stream>>>(source, fitB, tfitB, popB, trialB,
                                           out);
}

// Round 12
// 457.807 us; speedup vs baseline: 1.0218x; 1.0218x over previous
//
#include <hip/hip_runtime.h>
#include <stdint.h>

// ============================================================================
// JAX threefry2x32 PRNG reproduction (partitionable semantics, verified R0).
// ============================================================================
struct U2 { unsigned a, b; };

__device__ __forceinline__ unsigned rotl32(unsigned v, int r) {
  return (v << r) | (v >> (32 - r));
}

__device__ __forceinline__ U2 tf(U2 k, unsigned x0, unsigned x1) {
  unsigned ks0 = k.a, ks1 = k.b, ks2 = k.a ^ k.b ^ 0x1BD11BDAu;
  x0 += ks0; x1 += ks1;
#define TFG(RA, RB, RC, RD, KA, KB, INC)                  \
  x0 += x1; x1 = rotl32(x1, RA); x1 ^= x0;                \
  x0 += x1; x1 = rotl32(x1, RB); x1 ^= x0;                \
  x0 += x1; x1 = rotl32(x1, RC); x1 ^= x0;                \
  x0 += x1; x1 = rotl32(x1, RD); x1 ^= x0;                \
  x0 += KA; x1 += KB + INC;
  TFG(13, 15, 26, 6, ks1, ks2, 1u)
  TFG(17, 29, 16, 24, ks2, ks0, 2u)
  TFG(13, 15, 26, 6, ks0, ks1, 3u)
  TFG(17, 29, 16, 24, ks1, ks2, 4u)
  TFG(13, 15, 26, 6, ks2, ks0, 5u)
#undef TFG
  U2 r; r.a = x0; r.b = x1; return r;
}

__device__ __forceinline__ U2 split_key(U2 key, int num, int j) {
  (void)num;
  return tf(key, 0u, (unsigned)j);
}
__device__ __forceinline__ unsigned random_bits(U2 key, int n, unsigned e) {
  (void)n;
  U2 r = tf(key, 0u, e);
  return r.a ^ r.b;
}

__device__ __forceinline__ U2 root_key() { U2 k; k.a = 0u; k.b = 42u; return k; }

__device__ __forceinline__ float jax_uniform(U2 key, int n, unsigned e,
                                             float minv, float maxv) {
  unsigned b = random_bits(key, n, e);
  float u = __uint_as_float((b >> 9) | 0x3f800000u) - 1.0f;
  float r = u * (maxv - minv) + minv;
  return fmaxf(minv, r);
}

#define ROTR 0.7853981633974483f

__device__ __forceinline__ void compute_R(float vx, float vy, float vz,
                                          float R[3][3]) {
  float nsq = vx * vx + vy * vy + vz * vz;
  float theta = sqrtf(nsq);
  if (theta < 1e-8f) {
    R[0][0] = 1.f; R[0][1] = 0.f; R[0][2] = 0.f;
    R[1][0] = 0.f; R[1][1] = 1.f; R[1][2] = 0.f;
    R[2][0] = 0.f; R[2][1] = 0.f; R[2][2] = 1.f;
    return;
  }
  float m = fmaxf(theta, 1e-8f);
  float kx = vx / m, ky = vy / m, kz = vz / m;
  float s = sinf(theta), c = cosf(theta);
  float K[3][3] = {{0.f, -kz, ky}, {kz, 0.f, -kx}, {-ky, kx, 0.f}};
  float K2[3][3];
#pragma unroll
  for (int i = 0; i < 3; i++)
#pragma unroll
    for (int j = 0; j < 3; j++)
      K2[i][j] = fmaf(K[i][2], K[2][j], fmaf(K[i][1], K[1][j], K[i][0] * K[0][j]));
  float omc = 1.0f - c;
#pragma unroll
  for (int i = 0; i < 3; i++)
#pragma unroll
    for (int j = 0; j < 3; j++)
      R[i][j] = ((i == j) ? 1.0f : 0.0f) + s * K[i][j] + omc * K2[i][j];
}

// composite sort key for stream s (0:src r1, 1:src r2, 2:tgt r1, 3:tgt r2)
__device__ __forceinline__ unsigned long long make_composite(int s, int i) {
  U2 root = root_key();
  U2 kp = split_key(root, 5, s >> 1);
  U2 key;
  if ((s & 1) == 0) {
    key = split_key(kp, 2, 1);
  } else {
    U2 kA = split_key(kp, 2, 0);
    key = split_key(kA, 2, 1);
  }
  unsigned rb = random_bits(key, 16384, (unsigned)i);
  return ((unsigned long long)rb << 32) | (unsigned)i;
}

// ============================================================================
// Bucket-sort rank pipeline (verified R3-R6/R10) — WIDE dispatches.
// rank_kernel fuses the round-1 inverse scatter (even streams -> x1buf).
// ============================================================================
__global__ __launch_bounds__(256) void hist_kernel(unsigned* __restrict__ hist) {
  int gid = blockIdx.x * 256 + threadIdx.x;  // 65536
  int s = gid >> 14, i = gid & 16383;
  unsigned long long c = make_composite(s, i);
  unsigned bucket = (unsigned)(c >> 56);
  atomicAdd(&hist[s * 256 + bucket], 1u);
}

__global__ __launch_bounds__(256) void prefix_kernel(
    const unsigned* __restrict__ hist, unsigned* __restrict__ base,
    unsigned* __restrict__ cursor) {
  __shared__ unsigned h[4][256];
  int t = threadIdx.x;
#pragma unroll
  for (int s = 0; s < 4; s++) h[s][t] = hist[s * 256 + t];
  __syncthreads();
#pragma unroll
  for (int s = 0; s < 4; s++) {
    unsigned acc = 0;
    for (int j = 0; j < 256; j++) acc += (j < t) ? h[s][j] : 0u;
    base[s * 256 + t] = acc;
    cursor[s * 256 + t] = acc;
  }
}

__global__ __launch_bounds__(256) void scatterb_kernel(
    unsigned* __restrict__ cursor, unsigned long long* __restrict__ sorted) {
  int gid = blockIdx.x * 256 + threadIdx.x;  // 65536
  int s = gid >> 14, i = gid & 16383;
  unsigned long long c = make_composite(s, i);
  unsigned bucket = (unsigned)(c >> 56);
  unsigned pos = atomicAdd(&cursor[s * 256 + bucket], 1u);
  sorted[(s << 14) + pos] = c;
}

// rank; even streams (round 1) scatter x1 directly: x1[perm][rank] = i;
// odd streams (round 2) store rank for idx_kernel.
__global__ __launch_bounds__(256) void rank_kernel(
    const unsigned long long* __restrict__ sorted,
    const unsigned* __restrict__ base, const unsigned* __restrict__ hist,
    unsigned* __restrict__ rank_all, unsigned* __restrict__ x1buf) {
  int gid = blockIdx.x * 256 + threadIdx.x;  // 65536
  int s = gid >> 14, k = gid & 16383;
  unsigned long long c = sorted[(s << 14) + k];
  unsigned bucket = (unsigned)(c >> 56);
  unsigned b0 = base[s * 256 + bucket];
  unsigned cnt = hist[s * 256 + bucket];
  unsigned less = 0;
  for (unsigned j = 0; j < cnt; j++)
    less += (sorted[(s << 14) + b0 + j] < c) ? 1u : 0u;
  unsigned i = (unsigned)(c & 0xffffffffull);
  unsigned rank = b0 + less;
  if ((s & 1) == 0) x1buf[((s >> 1) << 14) + rank] = i;
  else              rank_all[(s << 14) + i] = rank;
}

__global__ __launch_bounds__(256) void idx_kernel(
    const unsigned* __restrict__ rank_all, const unsigned* __restrict__ x1buf,
    int* __restrict__ idx) {
  int gid = blockIdx.x * 256 + threadIdx.x;  // 32768
  int perm = gid >> 14, i = gid & 16383;
  unsigned r = rank_all[((perm * 2 + 1) << 14) + i];
  if (r < 128u) idx[perm * 128 + (int)r] = (int)x1buf[(perm << 14) + i];
}

// ============================================================================
// setup (blocks 0..31) + DE-schedule precompute (blocks 32..991).
// pack = i1 | i2<<6 | i3<<12 | mask<<18 ; STRIDED loops (verified R9/R10).
// ============================================================================
__global__ __launch_bounds__(128) void setupperm_kernel(
    const float* __restrict__ source, const float* __restrict__ target,
    const int* __restrict__ idx, float* __restrict__ src,
    float* __restrict__ tgt, float* __restrict__ yn,
    unsigned* __restrict__ packg) {
  int blk = blockIdx.x;
  int tid = threadIdx.x;
  if (blk < 32) {
    int b = blk;
    int is = idx[tid], it = idx[128 + tid];
#pragma unroll
    for (int d = 0; d < 3; d++)
      src[(b * 128 + tid) * 3 + d] = source[((size_t)b * 16384 + is) * 3 + d];
    float y0 = target[((size_t)b * 16384 + it) * 3 + 0];
    float y1 = target[((size_t)b * 16384 + it) * 3 + 1];
    float y2 = target[((size_t)b * 16384 + it) * 3 + 2];
    tgt[(b * 128 + tid) * 3 + 0] = y0;
    tgt[(b * 128 + tid) * 3 + 1] = y1;
    tgt[(b * 128 + tid) * 3 + 2] = y2;
    yn[b * 128 + tid] = y0 * y0 + y1 * y1 + y2 * y2;
    return;
  }
  int blk2 = blk - 32;  // 960
  int it = blk2 >> 5, b = blk2 & 31;
  __shared__ unsigned pbits[3][64];
  __shared__ int lperm[3][64];
  U2 root = root_key();
  U2 kloop = split_key(root, 5, 4);
  U2 kit = split_key(kloop, 30, it);
  U2 ka = split_key(kit, 3, 0);
  for (int e = tid; e < 150; e += 128) {
    int r = e / 50, q = e % 50;
    U2 pk = split_key(ka, 96, r * 32 + b);
    U2 sub = split_key(pk, 2, 1);
    pbits[r][q] = random_bits(sub, 50, (unsigned)q);
  }
  __syncthreads();
  for (int e = tid; e < 150; e += 128) {
    int r = e / 50, q = e % 50;
    unsigned bq = pbits[r][q];
    int cnt = 0;
    for (int j = 0; j < 50; j++) {
      unsigned bj = pbits[r][j];
      cnt += (bj < bq || (bj == bq && j < q)) ? 1 : 0;
    }
    lperm[r][cnt] = q;
  }
  __syncthreads();
  if (tid < 50) {
    int p = tid, bp = b * 50 + p;
    U2 kb = split_key(kit, 3, 1);
    U2 kc = split_key(kit, 3, 2);
    U2 kc1 = split_key(kc, 2, 0), kc2 = split_key(kc, 2, 1);
    unsigned hb = random_bits(kc1, 1600, (unsigned)bp);
    unsigned lb = random_bits(kc2, 1600, (unsigned)bp);
    int jr = (int)((((hb % 6u) * 4u) + (lb % 6u)) % 6u);
    unsigned mask = 0;
#pragma unroll
    for (int d = 0; d < 6; d++) {
      unsigned rb = random_bits(kb, 9600, (unsigned)(bp * 6 + d));
      float u = __uint_as_float((rb >> 9) | 0x3f800000u) - 1.0f;
      if ((u < 0.9f) || (d == jr)) mask |= (1u << d);
    }
    unsigned pack = (unsigned)lperm[0][p] | ((unsigned)lperm[1][p] << 6) |
                    ((unsigned)lperm[2][p] << 12) | (mask << 18);
    packg[(it * 32 + b) * 50 + p] = pack;
  }
}

// ============================================================================
// Chamfer eval core (verified R6 — bitwise identical d2/min/sum path).
// ============================================================================
__device__ __forceinline__ float eval_pose_core(
    float p0, float p1, float p2, float p3, float p4, float p5,
    float s0, float s1, float s2, int tid, const float4* syv, float4* xsv,
    float* rowpart, float* red1, float* red2) {
  float Rm[3][3];
  compute_R(p0, p1, p2, Rm);
  float x0 = fmaf(Rm[0][2], s2, fmaf(Rm[0][1], s1, Rm[0][0] * s0)) + p3;
  float x1 = fmaf(Rm[1][2], s2, fmaf(Rm[1][1], s1, Rm[1][0] * s0)) + p4;
  float x2 = fmaf(Rm[2][2], s2, fmaf(Rm[2][1], s1, Rm[2][0] * s0)) + p5;
  float xn = x0 * x0 + x1 * x1 + x2 * x2;
  xsv[tid] = make_float4(x0, x1, x2, xn);
  __syncthreads();
  int rg = tid & 31, cq = tid >> 5;
  float4 xr0 = xsv[4 * rg + 0];
  float4 xr1 = xsv[4 * rg + 1];
  float4 xr2 = xsv[4 * rg + 2];
  float4 xr3 = xsv[4 * rg + 3];
  float racc0 = 3.402823466e38f, racc1 = 3.402823466e38f;
  float racc2 = 3.402823466e38f, racc3 = 3.402823466e38f;
  float cacc[32];
#pragma unroll
  for (int cj = 0; cj < 32; cj++) {
    float4 y = syv[(cq << 5) + cj];
    float cr0 = fmaf(xr0.z, y.z, fmaf(xr0.y, y.y, xr0.x * y.x));
    float d0 = (xr0.w + y.w) - 2.0f * cr0; d0 = fmaxf(d0, 0.0f);
    float cr1 = fmaf(xr1.z, y.z, fmaf(xr1.y, y.y, xr1.x * y.x));
    float d1 = (xr1.w + y.w) - 2.0f * cr1; d1 = fmaxf(d1, 0.0f);
    float cr2 = fmaf(xr2.z, y.z, fmaf(xr2.y, y.y, xr2.x * y.x));
    float d2_ = (xr2.w + y.w) - 2.0f * cr2; d2_ = fmaxf(d2_, 0.0f);
    float cr3 = fmaf(xr3.z, y.z, fmaf(xr3.y, y.y, xr3.x * y.x));
    float d3 = (xr3.w + y.w) - 2.0f * cr3; d3 = fmaxf(d3, 0.0f);
    racc0 = fminf(racc0, d0); racc1 = fminf(racc1, d1);
    racc2 = fminf(racc2, d2_); racc3 = fminf(racc3, d3);
    cacc[cj] = fminf(fminf(d0, d1), fminf(d2_, d3));
  }
  rowpart[cq * 128 + 4 * rg + 0] = racc0;
  rowpart[cq * 128 + 4 * rg + 1] = racc1;
  rowpart[cq * 128 + 4 * rg + 2] = racc2;
  rowpart[cq * 128 + 4 * rg + 3] = racc3;
#pragma unroll
  for (int m = 16; m >= 1; m >>= 1) {
    bool hi = (rg & m) != 0;
#pragma unroll
    for (int j = 0; j < m; j++) {
      float lo_v = cacc[j], hi_v = cacc[j + m];
      float mine = hi ? hi_v : lo_v;
      float send = hi ? lo_v : hi_v;
      float recv = __shfl_xor(send, m, 64);
      cacc[j] = fminf(mine, recv);
    }
  }
  float colmin = cacc[0];
  __syncthreads();
  float rv = rowpart[tid];
  rv = fminf(rv, rowpart[128 + tid]);
  rv = fminf(rv, rowpart[256 + tid]);
  rv = fminf(rv, rowpart[384 + tid]);
  red1[tid] = rv;
  red2[tid] = colmin;
  __syncthreads();
  int l = tid & 63;
  float v1 = red1[l] + red1[l + 64];
  float v2 = red2[l] + red2[l + 64];
#pragma unroll
  for (int m = 32; m >= 1; m >>= 1) {
    v1 += __shfl_xor(v1, m, 64);
    v2 += __shfl_xor(v2, m, 64);
  }
  return v1 * 0.0078125f + v2 * 0.0078125f;
}

__device__ __forceinline__ float eff_pop(const float* pop_prev,
                                         const float* fit_prev,
                                         const float* trial_prev,
                                         const float* tfit_prev,
                                         int bq, int d) {
  return (tfit_prev[bq] < fit_prev[bq]) ? trial_prev[bq * 6 + d]
                                        : pop_prev[bq * 6 + d];
}

// pop0 value for particle r, dim d of batch b (pure function)
__device__ __forceinline__ float pop0_val(int b, int r, int d) {
  if (r == 0) return 0.0f;
  U2 root = root_key();
  unsigned ridx = (unsigned)((b * 50 + r) * 3 + (d % 3));
  if (d < 3) {
    U2 k2 = split_key(root, 5, 2);
    return jax_uniform(k2, 4800, ridx, -ROTR, ROTR);
  }
  U2 k3 = split_key(root, 5, 3);
  return jax_uniform(k3, 4800, ridx, -1.0f, 1.0f);
}

// ============================================================================
// fused DE step (verified R9/R10). init: pop0 recompute + both evals in step0.
// ============================================================================
__global__ __launch_bounds__(128, 4) void step_kernel(
    const float* __restrict__ srcb, const float* __restrict__ tgtb,
    const float* __restrict__ ynb, const unsigned* __restrict__ packg,
    const float* __restrict__ pop_prev, const float* __restrict__ fit_prev,
    const float* __restrict__ trial_prev, const float* __restrict__ tfit_prev,
    float* __restrict__ pop_cur, float* __restrict__ fit_cur,
    float* __restrict__ trial_cur, float* __restrict__ tfit_cur,
    int it, int init) {
  int blk = blockIdx.x;
  int b = blk / 50, p = blk % 50;
  int bp = blk;
  int tid = threadIdx.x;
  __shared__ float strial[8];
  __shared__ float pv4[4][6];
  __shared__ float4 syv[128];
  __shared__ float4 xsv[128];
  __shared__ float rowpart[512];
  __shared__ float red1[128];
  __shared__ float red2[128];

  {
    float y0 = tgtb[(b * 128 + tid) * 3 + 0];
    float y1 = tgtb[(b * 128 + tid) * 3 + 1];
    float y2 = tgtb[(b * 128 + tid) * 3 + 2];
    syv[tid] = make_float4(y0, y1, y2, ynb[b * 128 + tid]);
  }
  float s0 = srcb[(b * 128 + tid) * 3 + 0];
  float s1 = srcb[(b * 128 + tid) * 3 + 1];
  float s2 = srcb[(b * 128 + tid) * 3 + 2];

  unsigned pack = packg[(it * 32 + b) * 50 + p];
  int i1 = (int)(pack & 63u);
  int i2 = (int)((pack >> 6) & 63u);
  int i3 = (int)((pack >> 12) & 63u);
  unsigned mask = (pack >> 18) & 63u;

  if (init) {
    if (tid < 24) {
      int u = tid / 6, d = tid % 6;
      int rows[4] = {p, i1, i2, i3};
      pv4[u][d] = pop0_val(b, rows[u], d);
    }
    __syncthreads();
    float f0 = eval_pose_core(pv4[0][0], pv4[0][1], pv4[0][2], pv4[0][3],
                              pv4[0][4], pv4[0][5],
                              s0, s1, s2, tid, syv, xsv, rowpart, red1, red2);
    if (tid == 0) fit_cur[bp] = f0;
    if (tid < 6) {
      int d = tid;
      float mu = pv4[1][d] + 0.8f * (pv4[2][d] - pv4[3][d]);
      if (d < 3) mu = fminf(fmaxf(mu, -ROTR), ROTR);
      else       mu = fminf(fmaxf(mu, -1.0f), 1.0f);
      float pv = pv4[0][d];
      float tv = ((mask >> d) & 1u) ? mu : pv;
      strial[d] = tv;
      trial_cur[bp * 6 + d] = tv;
      pop_cur[bp * 6 + d] = pv;
    }
    __syncthreads();
    float f = eval_pose_core(strial[0], strial[1], strial[2], strial[3],
                             strial[4], strial[5],
                             s0, s1, s2, tid, syv, xsv, rowpart, red1, red2);
    if (tid == 0) tfit_cur[bp] = f;
    return;
  }

  if (tid < 6) {
    int d = tid;
    float x1v = eff_pop(pop_prev, fit_prev, trial_prev, tfit_prev, b * 50 + i1, d);
    float x2v = eff_pop(pop_prev, fit_prev, trial_prev, tfit_prev, b * 50 + i2, d);
    float x3v = eff_pop(pop_prev, fit_prev, trial_prev, tfit_prev, b * 50 + i3, d);
    float mu = x1v + 0.8f * (x2v - x3v);
    if (d < 3) mu = fminf(fmaxf(mu, -ROTR), ROTR);
    else       mu = fminf(fmaxf(mu, -1.0f), 1.0f);
    float pv = eff_pop(pop_prev, fit_prev, trial_prev, tfit_prev, bp, d);
    float tv = ((mask >> d) & 1u) ? mu : pv;
    strial[d] = tv;
    trial_cur[bp * 6 + d] = tv;
    pop_cur[bp * 6 + d] = pv;
  } else if (tid == 6) {
    float f = fit_prev[bp], tfv = tfit_prev[bp];
    fit_cur[bp] = (tfv < f) ? tfv : f;
  }
  __syncthreads();

  float f = eval_pose_core(strial[0], strial[1], strial[2], strial[3],
                           strial[4], strial[5],
                           s0, s1, s2, tid, syv, xsv, rowpart, red1, red2);
  if (tid == 0) tfit_cur[bp] = f;
}

// ============================================================================
// aligned + final selection fused (verified R6/R10).
// ============================================================================
__global__ __launch_bounds__(256) void aligned_kernel(
    const float* __restrict__ source, const float* __restrict__ fit,
    const float* __restrict__ tfit, const float* __restrict__ pop,
    const float* __restrict__ trial, float* __restrict__ out) {
  int blk = blockIdx.x;  // 2048; 64 blocks per batch
  int b = blk >> 6;
  int tid = threadIdx.x;
  __shared__ float fl[64];
  __shared__ float Rsh[12];
  if (tid < 50) {
    int bp = b * 50 + tid;
    float f = fit[bp], tfv = tfit[bp];
    fl[tid] = (tfv < f) ? tfv : f;
  }
  __syncthreads();
  if (tid == 0) {
    int best = 0;
    for (int q = 1; q < 50; q++)
      if (fl[q] < fl[best]) best = q;
    int bp = b * 50 + best;
    bool useT = tfit[bp] < fit[bp];
    const float* v = useT ? (trial + bp * 6) : (pop + bp * 6);
    float R[3][3];
    compute_R(v[0], v[1], v[2], R);
#pragma unroll
    for (int i = 0; i < 3; i++)
#pragma unroll
      for (int j = 0; j < 3; j++) Rsh[i * 3 + j] = R[i][j];
    Rsh[9] = v[3]; Rsh[10] = v[4]; Rsh[11] = v[5];
    if ((blk & 63) == 0) {
#pragma unroll
      for (int e = 0; e < 9; e++) out[b * 9 + e] = Rsh[e];
      out[288 + b * 3 + 0] = v[3];
      out[288 + b * 3 + 1] = v[4];
      out[288 + b * 3 + 2] = v[5];
    }
  }
  __syncthreads();
  int gid = blk * 256 + tid;  // 524288
  float s0 = source[(size_t)gid * 3 + 0];
  float s1 = source[(size_t)gid * 3 + 1];
  float s2 = source[(size_t)gid * 3 + 2];
  float a0 = fmaf(Rsh[2], s2, fmaf(Rsh[1], s1, Rsh[0] * s0)) + Rsh[9];
  float a1 = fmaf(Rsh[5], s2, fmaf(Rsh[4], s1, Rsh[3] * s0)) + Rsh[10];
  float a2 = fmaf(Rsh[8], s2, fmaf(Rsh[7], s1, Rsh[6] * s0)) + Rsh[11];
  out[384 + (size_t)gid * 3 + 0] = a0;
  out[384 + (size_t)gid * 3 + 1] = a1;
  out[384 + (size_t)gid * 3 + 2] = a2;
}

// ============================================================================
extern "C" void kernel_launch(void* const* d_in, const int* in_sizes, int n_in,
                              void* d_out, int out_size, void* d_ws,
                              size_t ws_size, hipStream_t stream) {
  const float* source = (const float*)d_in[0];
  const float* target = (const float*)d_in[1];
  float* out = (float*)d_out;
  char* ws = (char*)d_ws;

  // --- workspace layout, fully disjoint ---
  unsigned long long* sorted = (unsigned long long*)(ws + 0);   // 524288
  unsigned* rank_all = (unsigned*)(ws + 524288);                // 262144
  unsigned* x1buf    = (unsigned*)(ws + 786432);                // 131072
  int* idx           = (int*)(ws + 917504);                     // 1024
  unsigned* hist     = (unsigned*)(ws + 918528);                // 4096
  unsigned* basep    = (unsigned*)(ws + 922624);                // 4096
  unsigned* cursor   = (unsigned*)(ws + 926720);                // 4096
  unsigned* packg    = (unsigned*)(ws + 930816);                // 192000
  float* srcb        = (float*)(ws + 1122816);                  // 49152
  float* tgtb        = (float*)(ws + 1171968);                  // 49152
  float* ynb         = (float*)(ws + 1221120);                  // 16384
  float* popA        = (float*)(ws + 1237504);                  // 38400
  float* fitA        = (float*)(ws + 1275904);                  // 6400
  float* trialA      = (float*)(ws + 1282304);                  // 38400
  float* tfitA       = (float*)(ws + 1320704);                  // 6400
  float* popB        = (float*)(ws + 1327104);                  // 38400
  float* fitB        = (float*)(ws + 1365504);                  // 6400
  float* trialB      = (float*)(ws + 1371904);                  // 38400
  float* tfitB       = (float*)(ws + 1410304);                  // 6400

  hipMemsetAsync(hist, 0, 4096, stream);
  hist_kernel<<<256, 256, 0, stream>>>(hist);
  prefix_kernel<<<1, 256, 0, stream>>>(hist, basep, cursor);
  scatterb_kernel<<<256, 256, 0, stream>>>(cursor, sorted);
  rank_kernel<<<256, 256, 0, stream>>>(sorted, basep, hist, rank_all, x1buf);
  idx_kernel<<<128, 256, 0, stream>>>(rank_all, x1buf, idx);
  setupperm_kernel<<<992, 128, 0, stream>>>(source, target, idx, srcb, tgtb,
                                            ynb, packg);

  const float* pp = popA; const float* pf = fitA;
  const float* pt = trialA; const float* ptf = tfitA;
  for (int it = 0; it < 30; it++) {
    float* cp  = (it & 1) ? popB : popA;
    float* cf  = (it & 1) ? fitB : fitA;
    float* ct  = (it & 1) ? trialB : trialA;
    float* ctf = (it & 1) ? tfitB : tfitA;
    step_kernel<<<1600, 128, 0, stream>>>(srcb, tgtb, ynb, packg,
                                          pp, pf, pt, ptf,
                                          cp, cf, ct, ctf, it,
                                          (it == 0) ? 1 : 0);
    pp = cp; pf = cf; pt = ct; ptf = ctf;
  }
  // it=29 (odd) wrote the B buffers
  aligned_kernel<<<2048, 256, 0, stream>>>(source, fitB, tfitB, popB, trialB,
                                           out);
}